// Round 5
// baseline (40.207 us; speedup 1.0000x reference)
//
#include <hip/hip_runtime.h>

// Problem dims (fixed by setup_inputs)
constexpr int B = 2, C = 32, H = 96, W = 160, D = 32;
constexpr int HW = H * W;            // 15360
constexpr int NP = B * H * W;        // 30720 pixels
constexpr int WG = W / 4;            // 40 four-wide output groups per row
constexpr int PPB = 8;               // pixels per stage-1 block
constexpr float EPS = 1e-12f;

// ---------------------------------------------------------------------------
// Stage 1: per-pixel channel reductions.
//   sn[(b*D+d)*HW + hw] = { sum_c q*k , sum_c k*k }   (interleaved float2)
//   nq[b*HW + hw]       = sum_c q*q
// 128-thread blocks, 8 pixels/block -> 3840 blocks = exactly 15 waves/CU.
// 16 lanes per pixel: dg owns d = dg*4..dg*4+3, ch owns c-half.
// All 16 float4 k-loads are staged into registers BEFORE any FMA (16 KB in
// flight per wave); q comes from a 1 KB LDS slab loaded cooperatively, so the
// in-order vmcnt queue holds only k-loads during the hot phase.
// ---------------------------------------------------------------------------
__global__ __launch_bounds__(128) void dav_stage1(
    const float* __restrict__ q, const float* __restrict__ k,
    float2* __restrict__ sn, float* __restrict__ nq) {
  __shared__ float qs[C][PPB];       // 32 x 8 floats = 1 KB

  int blk = blockIdx.x;
  int b   = blk / (HW / PPB);        // 1920 blocks per batch image
  int hw0 = (blk % (HW / PPB)) * PPB;

  // Cooperative q load: thread -> (c = tid>>2, j = (tid&3)*2), one float2.
  {
    int c = threadIdx.x >> 2;
    int j = (threadIdx.x & 3) * 2;
    float2 v = *reinterpret_cast<const float2*>(
        q + (size_t)(b * C + c) * HW + hw0 + j);
    qs[c][j]     = v.x;
    qs[c][j + 1] = v.y;
  }
  __syncthreads();

  int lane16 = threadIdx.x & 15;
  int px = threadIdx.x >> 4;         // 0..7
  int dg = lane16 >> 1;              // d-group 0..7
  int ch = lane16 & 1;               // c-half
  int hw = hw0 + px;

  const float* kbase = k + ((size_t)(b * C + ch * 16) * HW + hw) * D + dg * 4;

  // Stage ALL k loads first -- statically indexed, stays in VGPRs.
  float4 kk[16];
#pragma unroll
  for (int c = 0; c < 16; ++c)
    kk[c] = *reinterpret_cast<const float4*>(kbase + (size_t)c * HW * D);

  float4 s4 = make_float4(0.f, 0.f, 0.f, 0.f);
  float4 n4 = make_float4(0.f, 0.f, 0.f, 0.f);
  float  nqv = 0.f;
#pragma unroll
  for (int c = 0; c < 16; ++c) {
    float qc = qs[ch * 16 + c][px];
    float4 k4 = kk[c];
    s4.x = fmaf(qc, k4.x, s4.x);
    s4.y = fmaf(qc, k4.y, s4.y);
    s4.z = fmaf(qc, k4.z, s4.z);
    s4.w = fmaf(qc, k4.w, s4.w);
    n4.x = fmaf(k4.x, k4.x, n4.x);
    n4.y = fmaf(k4.y, k4.y, n4.y);
    n4.z = fmaf(k4.z, k4.z, n4.z);
    n4.w = fmaf(k4.w, k4.w, n4.w);
    nqv  = fmaf(qc, qc, nqv);
  }

  // Combine the two c-halves across the lane pair.
  s4.x += __shfl_xor(s4.x, 1);
  s4.y += __shfl_xor(s4.y, 1);
  s4.z += __shfl_xor(s4.z, 1);
  s4.w += __shfl_xor(s4.w, 1);
  n4.x += __shfl_xor(n4.x, 1);
  n4.y += __shfl_xor(n4.y, 1);
  n4.z += __shfl_xor(n4.z, 1);
  n4.w += __shfl_xor(n4.w, 1);
  nqv  += __shfl_xor(nqv, 1);

  if (ch == 0) {
    size_t obase = ((size_t)(b * D + dg * 4)) * HW + hw;  // planar (B,D,H,W)
    sn[obase]          = make_float2(s4.x, n4.x);
    sn[obase + HW]     = make_float2(s4.y, n4.y);
    sn[obase + 2 * HW] = make_float2(s4.z, n4.z);
    sn[obase + 3 * HW] = make_float2(s4.w, n4.w);
    if (dg == 0) nq[(size_t)b * HW + hw] = nqv;
  }
}

// ---------------------------------------------------------------------------
// Stage 2: 3x3 box sums + normalize. 4 outputs (along w) per thread via
// shared column sums; q2 box computed inline from nq (L2-hot, 120 KB).
// (Unchanged from the passing R4 version.)
// ---------------------------------------------------------------------------
__global__ __launch_bounds__(256) void dav_stage2(
    const float2* __restrict__ sn, const float* __restrict__ nq,
    float* __restrict__ out) {
  int idx = blockIdx.x * 256 + threadIdx.x;
  if (idx >= B * D * H * WG) return;
  int g  = idx % WG;
  int h  = (idx / WG) % H;
  int bd = idx / (WG * H);   // b*D + d
  int b  = bd / D;
  int w0 = g * 4;

  float csS[6] = {0.f, 0.f, 0.f, 0.f, 0.f, 0.f};
  float csN[6] = {0.f, 0.f, 0.f, 0.f, 0.f, 0.f};
  float csQ[6] = {0.f, 0.f, 0.f, 0.f, 0.f, 0.f};
  const float2* plane  = sn + (size_t)bd * HW;
  const float*  qplane = nq + (size_t)b * HW;
#pragma unroll
  for (int r = -1; r <= 1; ++r) {
    int hh = h + r;
    if (hh < 0 || hh >= H) continue;
    const float2* row  = plane + hh * W;
    const float*  qrow = qplane + hh * W;
#pragma unroll
    for (int i = 0; i < 6; ++i) {
      int c = w0 - 1 + i;
      if (c >= 0 && c < W) {
        float2 v = row[c];
        csS[i] += v.x;
        csN[i] += v.y;
        csQ[i] += qrow[c];
      }
    }
  }

  float o[4];
#pragma unroll
  for (int i = 0; i < 4; ++i) {
    float dot = csS[i] + csS[i + 1] + csS[i + 2];
    float k2  = csN[i] + csN[i + 1] + csN[i + 2];
    float q2  = csQ[i] + csQ[i + 1] + csQ[i + 2];
    float dq  = fmaxf(sqrtf(q2), EPS);
    float dk  = fmaxf(sqrtf(k2), EPS);
    o[i] = dot / (dq * dk);
  }
  *reinterpret_cast<float4*>(out + (size_t)bd * HW + h * W + w0) =
      make_float4(o[0], o[1], o[2], o[3]);
}

extern "C" void kernel_launch(void* const* d_in, const int* in_sizes, int n_in,
                              void* d_out, int out_size, void* d_ws, size_t ws_size,
                              hipStream_t stream) {
  const float* q = (const float*)d_in[0];               // (B,C,H,W)
  const float* k = (const float*)d_in[1];               // (B,C,H,W,D)
  float* out = (float*)d_out;                           // (B,D,H,W)

  // Workspace layout: sn (float2, NP*D) | nq (float, NP)
  float2* sn = (float2*)d_ws;                           // 7.86 MB
  float*  nq = (float*)(sn + (size_t)NP * D);           // 0.12 MB

  {
    int blocks = NP / PPB;                  // 3840 = 15 waves/CU exactly
    dav_stage1<<<blocks, 128, 0, stream>>>(q, k, sn, nq);
  }
  {
    int n = B * D * H * WG;                 // 245760
    int blocks = (n + 255) / 256;           // 960
    dav_stage2<<<blocks, 256, 0, stream>>>(sn, nq, out);
  }
}